// Round 5
// baseline (385.361 us; speedup 1.0000x reference)
//
#include <hip/hip_runtime.h>

#define LOG2E 1.4426950408889634f

typedef short bf16x8 __attribute__((ext_vector_type(8)));
typedef float f32x4  __attribute__((ext_vector_type(4)));

#if defined(__has_builtin)
#if __has_builtin(__builtin_amdgcn_exp2f)
#define EXP2F(v) __builtin_amdgcn_exp2f(v)
#else
#define EXP2F(v) exp2f(v)
#endif
#else
#define EXP2F(v) exp2f(v)
#endif

// fp32 -> bf16 round-to-nearest-even
__device__ __forceinline__ unsigned short f2bf(float f) {
  unsigned u = __float_as_uint(f);
  u += 0x7fffu + ((u >> 16) & 1u);
  return (unsigned short)(u >> 16);
}
__device__ __forceinline__ float bf2f(unsigned short h) {
  return __uint_as_float(((unsigned)h) << 16);
}
// pack two fp32 -> bf16x2 (truncation; only used for softmax P weights)
__device__ __forceinline__ unsigned pack2bf(float lo, float hi) {
  return (__float_as_uint(hi) & 0xffff0000u) | (__float_as_uint(lo) >> 16);
}
__device__ __forceinline__ f32x4 mfma16(bf16x8 a, bf16x8 b, f32x4 c) {
  return __builtin_amdgcn_mfma_f32_16x16x32_bf16(a, b, c, 0, 0, 0);
}

// ---------------------------------------------------------------------------
// Projection (byte-identical to R4 -- held constant to isolate flash delta):
// x[B,128,4096] fp32 -> qk[B][N][32] bf16 (cols 0..15 = log2e*(Wq x + bq),
// 16..31 = Wk x + bk) and v[B][128][N] bf16.
// ---------------------------------------------------------------------------
__global__ __launch_bounds__(256, 2) void proj_kernel(
    const float* __restrict__ x,
    const float* __restrict__ Wq, const float* __restrict__ bq,
    const float* __restrict__ Wk, const float* __restrict__ bk,
    const float* __restrict__ Wv, const float* __restrict__ bv,
    unsigned short* __restrict__ qk, unsigned short* __restrict__ vout)
{
  const int b  = blockIdx.x & 7;
  const int n0 = (blockIdx.x >> 3) << 5;
  const int tid  = threadIdx.x;
  const int wave = tid >> 6;
  const int lane = tid & 63;
  const int l15  = lane & 15;
  const int quad = lane >> 4;

  __shared__ unsigned short Xt[32][136];   // [n][c], padded rows

  {
    const int nn = tid & 31, cg = tid >> 5;
    const float* xr = x + (size_t)b * 128 * 4096 + n0 + nn;
    float xv[16];
    #pragma unroll
    for (int t = 0; t < 16; ++t)
      xv[t] = xr[(size_t)(cg + (t << 3)) * 4096];
    #pragma unroll
    for (int t = 0; t < 16; ++t)
      Xt[nn][cg + (t << 3)] = f2bf(xv[t]);
  }
  __syncthreads();

  bf16x8 xa[2][4];
  #pragma unroll
  for (int rt = 0; rt < 2; ++rt)
    #pragma unroll
    for (int kt = 0; kt < 4; ++kt)
      xa[rt][kt] = *(const bf16x8*)&Xt[rt * 16 + l15][kt * 32 + quad * 8];

  const int nt0 = (wave < 2) ? wave * 3 : 6 + (wave - 2) * 2;
  const int ntc = (wave < 2) ? 3 : 2;

  f32x4 acc[2][3];
  #pragma unroll
  for (int rt = 0; rt < 2; ++rt)
    #pragma unroll
    for (int ni = 0; ni < 3; ++ni)
      acc[rt][ni] = (f32x4){0.f, 0.f, 0.f, 0.f};

  #pragma unroll
  for (int ni = 0; ni < 3; ++ni) {
    if (ni < ntc) {
      const int nt = nt0 + ni;
      const float* wrow;
      float sc = 1.f;
      if (nt == 0)      { wrow = Wq + l15 * 128; sc = LOG2E; }
      else if (nt == 1) { wrow = Wk + l15 * 128; }
      else              { wrow = Wv + (size_t)((nt - 2) * 16 + l15) * 128; }
      float4 wf[8];
      #pragma unroll
      for (int kt = 0; kt < 4; ++kt) {
        wf[2 * kt]     = *(const float4*)(wrow + kt * 32 + quad * 8);
        wf[2 * kt + 1] = *(const float4*)(wrow + kt * 32 + quad * 8 + 4);
      }
      #pragma unroll
      for (int kt = 0; kt < 4; ++kt) {
        const float4 f0 = wf[2 * kt], f1 = wf[2 * kt + 1];
        bf16x8 wb;
        wb[0] = (short)f2bf(sc * f0.x); wb[1] = (short)f2bf(sc * f0.y);
        wb[2] = (short)f2bf(sc * f0.z); wb[3] = (short)f2bf(sc * f0.w);
        wb[4] = (short)f2bf(sc * f1.x); wb[5] = (short)f2bf(sc * f1.y);
        wb[6] = (short)f2bf(sc * f1.z); wb[7] = (short)f2bf(sc * f1.w);
        #pragma unroll
        for (int rt = 0; rt < 2; ++rt)
          acc[rt][ni] = mfma16(xa[rt][kt], wb, acc[rt][ni]);
      }
    }
  }

  #pragma unroll
  for (int ni = 0; ni < 3; ++ni) {
    if (ni < ntc) {
      const int nt = nt0 + ni;
      if (nt < 2) {
        const float bias = (nt == 0) ? LOG2E * bq[l15] : bk[l15];
        #pragma unroll
        for (int rt = 0; rt < 2; ++rt) {
          const int nb = n0 + rt * 16 + quad * 4;
          #pragma unroll
          for (int r = 0; r < 4; ++r)
            qk[((size_t)b * 4096 + nb + r) * 32 + nt * 16 + l15] =
                f2bf(acc[rt][ni][r] + bias);
        }
      } else {
        const int c = (nt - 2) * 16 + l15;
        const float bias = bv[c];
        #pragma unroll
        for (int rt = 0; rt < 2; ++rt) {
          const int nb = n0 + rt * 16 + quad * 4;
          ushort4 pk;
          pk.x = f2bf(acc[rt][ni][0] + bias);
          pk.y = f2bf(acc[rt][ni][1] + bias);
          pk.z = f2bf(acc[rt][ni][2] + bias);
          pk.w = f2bf(acc[rt][ni][3] + bias);
          *(ushort4*)&vout[((size_t)b * 128 + c) * 4096 + nb] = pk;
        }
      }
    }
  }
}

// ---------------------------------------------------------------------------
// Flash attention, R5: j-split-4 for TLP.
// No-max softmax (p = exp2(s); bounded scores, partials ADD exactly).
// Grid 1024 = 8 b (blk&7, XCD-pinned) x 128 row-groups of 32. Block 256 =
// 4 waves; wave w = j-quarter (1024 j, 8 iters of 128). All 4 waves share the
// block's 32 rows (2 row-tiles A/B); partial (O,l) summed 4-way at the end.
// -> 4 blocks/CU, 16 waves/CU, 4 waves/SIMD (R4's grid capped at 2/SIMD and
// all pipes sat idle on queued L2 latency; VGPR=128 already permits 4/SIMD).
// Per-wave dataflow identical to R4: batched K-frag + V-frag loads, S^T via
// MFMA (A=K,B=Q), exp2, swizzled-LDS P, PV MFMA from global V fragments.
// ---------------------------------------------------------------------------
__global__ __launch_bounds__(256, 4) void flash_kernel(
    const unsigned short* __restrict__ qk,
    const unsigned short* __restrict__ v,
    const float* __restrict__ x,
    const float* __restrict__ gamma,
    float* __restrict__ out)
{
  const int b     = blockIdx.x & 7;
  const int rows0 = (blockIdx.x >> 3) << 5;
  const int tid  = threadIdx.x;
  const int w    = tid >> 6;        // j-quarter
  const int lane = tid & 63;
  const int l15  = lane & 15;
  const int quad = lane >> 4;

  // per-wave region: P tiles A,B (2 x 16x128 sh = 4096 sh), reused as O-stage
  // (32 rows x 136 sh = 4352 sh). 8704 B per wave.
  __shared__ unsigned short R[4][4352];
  __shared__ float La[4][32];

  const unsigned short* qkb = qk + (size_t)b * 4096 * 32;

  bf16x8 qa0 = {0, 0, 0, 0, 0, 0, 0, 0};
  bf16x8 qa1 = {0, 0, 0, 0, 0, 0, 0, 0};
  if (quad < 2) {
    qa0 = *(const bf16x8*)(qkb + (size_t)(rows0 + l15) * 32 + quad * 8);
    qa1 = *(const bf16x8*)(qkb + (size_t)(rows0 + 16 + l15) * 32 + quad * 8);
  }

  f32x4 oA[8], oB[8];
  #pragma unroll
  for (int nt = 0; nt < 8; ++nt) {
    oA[nt] = (f32x4){0.f, 0.f, 0.f, 0.f};
    oB[nt] = (f32x4){0.f, 0.f, 0.f, 0.f};
  }
  float lsA = 0.f, lsB = 0.f;

  unsigned short* PA = &R[w][0];
  unsigned short* PB = &R[w][2048];
  const unsigned short* vrow =
      v + (size_t)b * 128 * 4096 + (size_t)l15 * 4096 + quad * 8;
  const int swz = l15 & 7;
  const f32x4 zf = (f32x4){0.f, 0.f, 0.f, 0.f};

  for (int t = 0; t < 8; ++t) {
    const int jbase = w * 1024 + t * 128;
    const unsigned short* kb0 = qkb + (size_t)jbase * 32 + 16 + quad * 8;
    const unsigned short* vj  = vrow + jbase;

    // K-frag batch (8 in flight; quads 2,3 read garbage x qa-zero = 0)
    bf16x8 kbr[8];
    #pragma unroll
    for (int ct = 0; ct < 8; ++ct)
      kbr[ct] = *(const bf16x8*)(kb0 + (size_t)(ct * 16 + l15) * 32);
    // V kt=0 batch
    bf16x8 va0[8];
    #pragma unroll
    for (int nt = 0; nt < 8; ++nt)
      va0[nt] = *(const bf16x8*)(vj + (size_t)nt * 16 * 4096);

    // S^T tile A: lane holds S[j=ct*16+quad*4+r][i=l15]
    f32x4 s[8];
    #pragma unroll
    for (int ct = 0; ct < 8; ++ct) s[ct] = mfma16(kbr[ct], qa0, zf);

    bf16x8 va1[8];
    #pragma unroll
    for (int nt = 0; nt < 8; ++nt)
      va1[nt] = *(const bf16x8*)(vj + (size_t)nt * 16 * 4096 + 32);

    // pack A: p = exp2(s), swizzled 8B LDS writes
    #pragma unroll
    for (int ct = 0; ct < 8; ++ct) {
      const float p0 = EXP2F(s[ct][0]);
      const float p1 = EXP2F(s[ct][1]);
      const float p2 = EXP2F(s[ct][2]);
      const float p3 = EXP2F(s[ct][3]);
      lsA += (p0 + p1) + (p2 + p3);
      uint2 d;
      d.x = pack2bf(p0, p1);
      d.y = pack2bf(p2, p3);
      *(uint2*)(PA + l15 * 128 +
                ((((ct * 2 + (quad >> 1)) ^ swz) << 3) + ((quad & 1) << 2))) = d;
    }

    // S^T tile B (reuses kbr)
    #pragma unroll
    for (int ct = 0; ct < 8; ++ct) s[ct] = mfma16(kbr[ct], qa1, zf);

    #pragma unroll
    for (int ct = 0; ct < 8; ++ct) {
      const float p0 = EXP2F(s[ct][0]);
      const float p1 = EXP2F(s[ct][1]);
      const float p2 = EXP2F(s[ct][2]);
      const float p3 = EXP2F(s[ct][3]);
      lsB += (p0 + p1) + (p2 + p3);
      uint2 d;
      d.x = pack2bf(p0, p1);
      d.y = pack2bf(p2, p3);
      *(uint2*)(PB + l15 * 128 +
                ((((ct * 2 + (quad >> 1)) ^ swz) << 3) + ((quad & 1) << 2))) = d;
    }

    bf16x8 va2[8];
    #pragma unroll
    for (int nt = 0; nt < 8; ++nt)
      va2[nt] = *(const bf16x8*)(vj + (size_t)nt * 16 * 4096 + 64);

    // PV kt=0 (va0 longest in flight); each V-frag feeds 2 MFMAs
    {
      const int rc = ((0 + quad) ^ swz) << 3;
      const bf16x8 pA = *(const bf16x8*)(PA + l15 * 128 + rc);
      const bf16x8 pB = *(const bf16x8*)(PB + l15 * 128 + rc);
      #pragma unroll
      for (int nt = 0; nt < 8; ++nt) {
        oA[nt] = mfma16(pA, va0[nt], oA[nt]);
        oB[nt] = mfma16(pB, va0[nt], oB[nt]);
      }
    }
    bf16x8 va3[8];
    #pragma unroll
    for (int nt = 0; nt < 8; ++nt)
      va3[nt] = *(const bf16x8*)(vj + (size_t)nt * 16 * 4096 + 96);
    {
      const int rc = ((4 + quad) ^ swz) << 3;
      const bf16x8 pA = *(const bf16x8*)(PA + l15 * 128 + rc);
      const bf16x8 pB = *(const bf16x8*)(PB + l15 * 128 + rc);
      #pragma unroll
      for (int nt = 0; nt < 8; ++nt) {
        oA[nt] = mfma16(pA, va1[nt], oA[nt]);
        oB[nt] = mfma16(pB, va1[nt], oB[nt]);
      }
    }
    {
      const int rc = ((8 + quad) ^ swz) << 3;
      const bf16x8 pA = *(const bf16x8*)(PA + l15 * 128 + rc);
      const bf16x8 pB = *(const bf16x8*)(PB + l15 * 128 + rc);
      #pragma unroll
      for (int nt = 0; nt < 8; ++nt) {
        oA[nt] = mfma16(pA, va2[nt], oA[nt]);
        oB[nt] = mfma16(pB, va2[nt], oB[nt]);
      }
    }
    {
      const int rc = ((12 + quad) ^ swz) << 3;
      const bf16x8 pA = *(const bf16x8*)(PA + l15 * 128 + rc);
      const bf16x8 pB = *(const bf16x8*)(PB + l15 * 128 + rc);
      #pragma unroll
      for (int nt = 0; nt < 8; ++nt) {
        oA[nt] = mfma16(pA, va3[nt], oA[nt]);
        oB[nt] = mfma16(pB, va3[nt], oB[nt]);
      }
    }
  }

  // ---- l reduction across quads (each lane's partial is for row i=l15) ----
  lsA += __shfl_xor(lsA, 16); lsA += __shfl_xor(lsA, 32);
  lsB += __shfl_xor(lsB, 16); lsB += __shfl_xor(lsB, 32);
  if (lane < 16) {
    La[w][lane]      = lsA;
    La[w][16 + lane] = lsB;
  }

  // ---- stage O to LDS (overwrites own P region; row stride 136 sh) ----
  {
    unsigned short* SG = &R[w][0];
    #pragma unroll
    for (int nt = 0; nt < 8; ++nt) {
      const int c = nt * 16 + l15;
      #pragma unroll
      for (int r = 0; r < 4; ++r) {
        SG[(quad * 4 + r) * 136 + c]      = f2bf(oA[nt][r]);
        SG[(16 + quad * 4 + r) * 136 + c] = f2bf(oB[nt][r]);
      }
    }
  }
  __syncthreads();

  // ---- epilogue: thread = (ig = tid&7 -> 4 rows, cb = tid>>3 -> 4 c) ----
  // 4-way partial sum over wave regions; stores 128B-contiguous per 8 lanes.
  {
    const int ig = tid & 7;
    const int cb = tid >> 3;
    const float g = gamma[0];
    float rl[4];
    #pragma unroll
    for (int r = 0; r < 4; ++r) {
      const int rw = ig * 4 + r;
      rl[r] = 1.f / (La[0][rw] + La[1][rw] + La[2][rw] + La[3][rw]);
    }
    #pragma unroll
    for (int k = 0; k < 4; ++k) {
      const int c = cb * 4 + k;
      const size_t off = ((size_t)b * 128 + c) * 4096 + rows0 + ig * 4;
      const float4 xv = *(const float4*)(x + off);
      float4 ov;
      float* pov = &ov.x;
      const float* pxv = &xv.x;
      #pragma unroll
      for (int r = 0; r < 4; ++r) {
        const int rw = ig * 4 + r;
        const float oo = bf2f(R[0][rw * 136 + c]) + bf2f(R[1][rw * 136 + c]) +
                         bf2f(R[2][rw * 136 + c]) + bf2f(R[3][rw * 136 + c]);
        pov[r] = g * (oo * rl[r]) + pxv[r];
      }
      *(float4*)(out + off) = ov;
    }
  }
}

extern "C" void kernel_launch(void* const* d_in, const int* in_sizes, int n_in,
                              void* d_out, int out_size, void* d_ws, size_t ws_size,
                              hipStream_t stream) {
  const float* x     = (const float*)d_in[0];
  const float* Wq    = (const float*)d_in[1];
  const float* bq    = (const float*)d_in[2];
  const float* Wk    = (const float*)d_in[3];
  const float* bk    = (const float*)d_in[4];
  const float* Wv    = (const float*)d_in[5];
  const float* bv    = (const float*)d_in[6];
  const float* gamma = (const float*)d_in[7];
  float* out = (float*)d_out;

  unsigned short* qkb = (unsigned short*)d_ws;         // 8*4096*32 bf16 = 2 MB
  unsigned short* vb  = qkb + (size_t)8 * 4096 * 32;   // 8*128*4096 bf16 = 8 MB

  proj_kernel<<<1024, 256, 0, stream>>>(x, Wq, bq, Wk, bk, Wv, bv, qkb, vb);
  flash_kernel<<<1024, 256, 0, stream>>>(qkb, vb, x, gamma, out);
}

// Round 6
// 155.647 us; speedup vs baseline: 2.4759x; 2.4759x over previous
//
#include <hip/hip_runtime.h>

#define LOG2E 1.4426950408889634f

typedef short bf16x8  __attribute__((ext_vector_type(8)));
typedef float f32x4   __attribute__((ext_vector_type(4)));
typedef float f32x16  __attribute__((ext_vector_type(16)));
typedef unsigned int u32x4 __attribute__((ext_vector_type(4)));

#if defined(__has_builtin)
#if __has_builtin(__builtin_amdgcn_exp2f)
#define EXP2F(v) __builtin_amdgcn_exp2f(v)
#else
#define EXP2F(v) exp2f(v)
#endif
#else
#define EXP2F(v) exp2f(v)
#endif

// fp32 -> bf16 round-to-nearest-even
__device__ __forceinline__ unsigned short f2bf(float f) {
  unsigned u = __float_as_uint(f);
  u += 0x7fffu + ((u >> 16) & 1u);
  return (unsigned short)(u >> 16);
}
// pack two fp32 -> bf16x2 (truncation; softmax weights only)
__device__ __forceinline__ unsigned pack2bf(float lo, float hi) {
  return (__float_as_uint(hi) & 0xffff0000u) | (__float_as_uint(lo) >> 16);
}
__device__ __forceinline__ f32x4 mfma16(bf16x8 a, bf16x8 b, f32x4 c) {
  return __builtin_amdgcn_mfma_f32_16x16x32_bf16(a, b, c, 0, 0, 0);
}
__device__ __forceinline__ f32x16 mfma32(bf16x8 a, bf16x8 b, f32x16 c) {
  return __builtin_amdgcn_mfma_f32_32x32x16_bf16(a, b, c, 0, 0, 0);
}
// global -> LDS direct DMA, 16 B per lane at ldsbase + lane*16
__device__ __forceinline__ void load_lds16(const unsigned short* g,
                                           unsigned short* l) {
  __builtin_amdgcn_global_load_lds(
      (const __attribute__((address_space(1))) unsigned int*)g,
      (__attribute__((address_space(3))) unsigned int*)l, 16, 0, 0);
}

// ---------------------------------------------------------------------------
// Projection (R5 structure; ONLY change: V store address gets a 16B-chunk XOR
// swizzle within each 128-j tile so flash's straight global->LDS DMA copy
// yields a bank-conflict-free tile):
// x[B,128,4096] fp32 -> qk[B][N][32] bf16 (0..15 = log2e*(Wq x + bq),
// 16..31 = Wk x + bk) and v[B][128][N'] bf16 with j' chunk-swizzled.
// ---------------------------------------------------------------------------
__global__ __launch_bounds__(256, 2) void proj_kernel(
    const float* __restrict__ x,
    const float* __restrict__ Wq, const float* __restrict__ bq,
    const float* __restrict__ Wk, const float* __restrict__ bk,
    const float* __restrict__ Wv, const float* __restrict__ bv,
    unsigned short* __restrict__ qk, unsigned short* __restrict__ vout)
{
  const int b  = blockIdx.x & 7;
  const int n0 = (blockIdx.x >> 3) << 5;
  const int tid  = threadIdx.x;
  const int wave = tid >> 6;
  const int lane = tid & 63;
  const int l15  = lane & 15;
  const int quad = lane >> 4;

  __shared__ unsigned short Xt[32][136];   // [n][c], padded rows

  {
    const int nn = tid & 31, cg = tid >> 5;
    const float* xr = x + (size_t)b * 128 * 4096 + n0 + nn;
    float xv[16];
    #pragma unroll
    for (int t = 0; t < 16; ++t)
      xv[t] = xr[(size_t)(cg + (t << 3)) * 4096];
    #pragma unroll
    for (int t = 0; t < 16; ++t)
      Xt[nn][cg + (t << 3)] = f2bf(xv[t]);
  }
  __syncthreads();

  bf16x8 xa[2][4];
  #pragma unroll
  for (int rt = 0; rt < 2; ++rt)
    #pragma unroll
    for (int kt = 0; kt < 4; ++kt)
      xa[rt][kt] = *(const bf16x8*)&Xt[rt * 16 + l15][kt * 32 + quad * 8];

  const int nt0 = (wave < 2) ? wave * 3 : 6 + (wave - 2) * 2;
  const int ntc = (wave < 2) ? 3 : 2;

  f32x4 acc[2][3];
  #pragma unroll
  for (int rt = 0; rt < 2; ++rt)
    #pragma unroll
    for (int ni = 0; ni < 3; ++ni)
      acc[rt][ni] = (f32x4){0.f, 0.f, 0.f, 0.f};

  #pragma unroll
  for (int ni = 0; ni < 3; ++ni) {
    if (ni < ntc) {
      const int nt = nt0 + ni;
      const float* wrow;
      float sc = 1.f;
      if (nt == 0)      { wrow = Wq + l15 * 128; sc = LOG2E; }
      else if (nt == 1) { wrow = Wk + l15 * 128; }
      else              { wrow = Wv + (size_t)((nt - 2) * 16 + l15) * 128; }
      float4 wf[8];
      #pragma unroll
      for (int kt = 0; kt < 4; ++kt) {
        wf[2 * kt]     = *(const float4*)(wrow + kt * 32 + quad * 8);
        wf[2 * kt + 1] = *(const float4*)(wrow + kt * 32 + quad * 8 + 4);
      }
      #pragma unroll
      for (int kt = 0; kt < 4; ++kt) {
        const float4 f0 = wf[2 * kt], f1 = wf[2 * kt + 1];
        bf16x8 wb;
        wb[0] = (short)f2bf(sc * f0.x); wb[1] = (short)f2bf(sc * f0.y);
        wb[2] = (short)f2bf(sc * f0.z); wb[3] = (short)f2bf(sc * f0.w);
        wb[4] = (short)f2bf(sc * f1.x); wb[5] = (short)f2bf(sc * f1.y);
        wb[6] = (short)f2bf(sc * f1.z); wb[7] = (short)f2bf(sc * f1.w);
        #pragma unroll
        for (int rt = 0; rt < 2; ++rt)
          acc[rt][ni] = mfma16(xa[rt][kt], wb, acc[rt][ni]);
      }
    }
  }

  #pragma unroll
  for (int ni = 0; ni < 3; ++ni) {
    if (ni < ntc) {
      const int nt = nt0 + ni;
      if (nt < 2) {
        const float bias = (nt == 0) ? LOG2E * bq[l15] : bk[l15];
        #pragma unroll
        for (int rt = 0; rt < 2; ++rt) {
          const int nb = n0 + rt * 16 + quad * 4;
          #pragma unroll
          for (int r = 0; r < 4; ++r)
            qk[((size_t)b * 4096 + nb + r) * 32 + nt * 16 + l15] =
                f2bf(acc[rt][ni][r] + bias);
        }
      } else {
        const int c = (nt - 2) * 16 + l15;
        const float bias = bv[c];
        #pragma unroll
        for (int rt = 0; rt < 2; ++rt) {
          const int nb = n0 + rt * 16 + quad * 4;
          // chunk-swizzle within the 128-j tile: cj' = cj ^ (c & 7)
          const int cj    = (nb >> 3) & 15;
          const int nb_sw = (nb & ~127) | (((cj ^ (c & 7)) << 3)) | (nb & 7);
          ushort4 pk;
          pk.x = f2bf(acc[rt][ni][0] + bias);
          pk.y = f2bf(acc[rt][ni][1] + bias);
          pk.z = f2bf(acc[rt][ni][2] + bias);
          pk.w = f2bf(acc[rt][ni][3] + bias);
          *(ushort4*)&vout[((size_t)b * 128 + c) * 4096 + nb_sw] = pk;
        }
      }
    }
  }
}

// ---------------------------------------------------------------------------
// Flash attention R6: 32x32x16 MFMA + LDS V-staging via global_load_lds.
// No-max softmax (bounded scores; partials add exactly).
// Grid 1024 = 8 b (XCD-pinned) x 32 rowgroups(128) x 4 j-quarters. Block 256
// = 4 waves, wave = 32 rows; 8 iters of 128 j.
// Per iter: K-frags (4 dense 16B global loads, issued pre-barrier) ->
// sync -> V tile DMA (32 KB, 8 global_load_lds/wave, zero VGPRs) ->
// S^T = mfma32(K, Q) (K=16 exact, no padding) -> exp2 -> in-register
// D-layout->A-layout transpose (8 shfl_xor(32)/tile; only the 4*(lane>=32)
// row offset crosses lanes) -> sync -> PV: 32 ds_read_b128 B-frags (uniform
// 8-per-bank-quad via global chunk swizzle) x 32 mfma32.
// VGPR ~160 (o 64 + A 32 + kf 16 + transients) -> 3 waves/SIMD.
// ---------------------------------------------------------------------------
__global__ __launch_bounds__(256, 3) void flash_kernel(
    const unsigned short* __restrict__ qk,
    const unsigned short* __restrict__ v,
    const float* __restrict__ x,
    const float* __restrict__ gamma,
    float* __restrict__ out)
{
  const int blk = blockIdx.x;
  const int b   = blk & 7;
  const int rg  = (blk >> 3) & 31;
  const int jh  = blk >> 8;            // 0..3
  const int tid  = threadIdx.x;
  const int w    = tid >> 6;
  const int lane = tid & 63;
  const int il   = lane & 31;
  const int h    = lane >> 5;

  __shared__ unsigned short Vt[128 * 128];   // 32 KB: [c][16B-chunk swizzled j]

  const unsigned short* qkb = qk + (size_t)b * 4096 * 32;
  const unsigned short* vbB = v + (size_t)b * 128 * 4096;
  const int i0w = rg * 128 + w * 32;

  // Q B-frag: lane -> col i = il, k = h*8 + e (dense, all 64 lanes useful)
  const bf16x8 qa = *(const bf16x8*)(qkb + (size_t)(i0w + il) * 32 + h * 8);

  f32x16 o[4];
  #pragma unroll
  for (int ct = 0; ct < 4; ++ct)
    #pragma unroll
    for (int e = 0; e < 16; ++e) o[ct][e] = 0.f;
  float lsum = 0.f;

  const f32x16 z16 = o[0];
  const int sc_row = lane >> 4;            // staging: row within 4-row group
  const int sc_col = (lane & 15) * 8;      // staging: chunk col (shorts)

  for (int t = 0; t < 8; ++t) {
    const int jbase = jh * 1024 + t * 128;

    // K A-frags: lane -> row j = jt*32+il, k = h*8+e. Global, pre-barrier
    // (no LDS hazard), latency covered by prev PV + S phase.
    bf16x8 kf[4];
    #pragma unroll
    for (int jt = 0; jt < 4; ++jt)
      kf[jt] = *(const bf16x8*)(qkb + (size_t)(jbase + jt * 32 + il) * 32 +
                                16 + h * 8);

    __syncthreads();   // all waves done reading Vt(t-1)

    // V tile DMA: straight copy of (chunk-swizzled) global rows -> LDS
    #pragma unroll
    for (int k = 0; k < 8; ++k) {
      const int cbase = w * 32 + k * 4;
      load_lds16(vbB + (size_t)(cbase + sc_row) * 4096 + jbase + sc_col,
                 &Vt[cbase * 128]);
    }

    // S^T tiles + exp2 + in-register transpose to PV A-frags
    u32x4 A[8];
    #pragma unroll
    for (int jt = 0; jt < 4; ++jt) {
      f32x16 s = mfma32(kf[jt], qa, z16);
      float p[16];
      #pragma unroll
      for (int e = 0; e < 16; ++e) p[e] = EXP2F(s[e]);
      #pragma unroll
      for (int e = 0; e < 16; ++e) lsum += p[e];
      unsigned u[8], su[8];
      #pragma unroll
      for (int q = 0; q < 8; ++q) {
        u[q]  = pack2bf(p[2 * q], p[2 * q + 1]);
        su[q] = __shfl_xor(u[q], 32);
      }
      // A[jc] covers j = jt*32 + jc16*16 + h*8 + 0..7 for row i = il
      A[2 * jt]     = h ? (u32x4){su[2], su[3], u[2], u[3]}
                        : (u32x4){u[0], u[1], su[0], su[1]};
      A[2 * jt + 1] = h ? (u32x4){su[6], su[7], u[6], u[7]}
                        : (u32x4){u[4], u[5], su[4], su[5]};
    }

    __syncthreads();   // Vt(t) ready (drains DMA vmcnt)

    // PV: B-frag = V[c = ct*32+il][j chunk], swizzled LDS read
    #pragma unroll
    for (int jc = 0; jc < 8; ++jc) {
      const bf16x8 pa = __builtin_bit_cast(bf16x8, A[jc]);
      #pragma unroll
      for (int ct = 0; ct < 4; ++ct) {
        const bf16x8 vb = *(const bf16x8*)&Vt[(ct * 32 + il) * 128 +
                                              (((jc * 2 + h) ^ (il & 7)) << 3)];
        o[ct] = mfma32(pa, vb, o[ct]);
      }
    }
  }

  // ---- softmax denominator ----
  lsum += __shfl_xor(lsum, 32);            // lane il now holds l for row il
  float rl[16];
  #pragma unroll
  for (int e = 0; e < 16; ++e) {
    const int row = 4 * h + (e & 3) + 8 * (e >> 2);
    rl[e] = 1.f / __shfl(lsum, row);
  }

  // ---- epilogue: gamma * O/l + x ----
  const float g = gamma[0];
  #pragma unroll
  for (int ct = 0; ct < 4; ++ct) {
    const int c = ct * 32 + il;
    const size_t rowoff = ((size_t)b * 128 + c) * 4096 + i0w + 4 * h;
    #pragma unroll
    for (int rq = 0; rq < 4; ++rq) {
      const size_t idx = rowoff + rq * 8;
      const float4 xv = *(const float4*)(x + idx);
      float4 ov;
      ov.x = g * (o[ct][rq * 4 + 0] * rl[rq * 4 + 0]) + xv.x;
      ov.y = g * (o[ct][rq * 4 + 1] * rl[rq * 4 + 1]) + xv.y;
      ov.z = g * (o[ct][rq * 4 + 2] * rl[rq * 4 + 2]) + xv.z;
      ov.w = g * (o[ct][rq * 4 + 3] * rl[rq * 4 + 3]) + xv.w;
      *(float4*)(out + idx) = ov;
    }
  }
}

extern "C" void kernel_launch(void* const* d_in, const int* in_sizes, int n_in,
                              void* d_out, int out_size, void* d_ws, size_t ws_size,
                              hipStream_t stream) {
  const float* x     = (const float*)d_in[0];
  const float* Wq    = (const float*)d_in[1];
  const float* bq    = (const float*)d_in[2];
  const float* Wk    = (const float*)d_in[3];
  const float* bk    = (const float*)d_in[4];
  const float* Wv    = (const float*)d_in[5];
  const float* bv    = (const float*)d_in[6];
  const float* gamma = (const float*)d_in[7];
  float* out = (float*)d_out;

  unsigned short* qkb = (unsigned short*)d_ws;         // 8*4096*32 bf16 = 2 MB
  unsigned short* vb  = qkb + (size_t)8 * 4096 * 32;   // 8*128*4096 bf16 = 8 MB

  proj_kernel<<<1024, 256, 0, stream>>>(x, Wq, bq, Wk, bk, Wv, bv, qkb, vb);
  flash_kernel<<<1024, 256, 0, stream>>>(qkb, vb, x, gamma, out);
}